// Round 4
// baseline (988.513 us; speedup 1.0000x reference)
//
#include <hip/hip_runtime.h>
#include <hip/hip_bf16.h>
#include <math.h>

typedef __attribute__((ext_vector_type(8))) __bf16 bf16x8;
typedef __attribute__((ext_vector_type(4))) float f32x4;

#define MFMA16(a, b, c) __builtin_amdgcn_mfma_f32_16x16x32_bf16((a), (b), (c), 0, 0, 0)

__device__ inline void gld_lds16(const __hip_bfloat16* g, __hip_bfloat16* l) {
    __builtin_amdgcn_global_load_lds(
        (const __attribute__((address_space(1))) void*)g,
        (__attribute__((address_space(3))) void*)l, 16, 0, 0);
}

#define RAW_BARRIER() __builtin_amdgcn_s_barrier()
#define WAIT_LGKM0()                                          \
    do {                                                      \
        asm volatile("s_waitcnt lgkmcnt(0)" ::: "memory");    \
        __builtin_amdgcn_sched_barrier(0);                    \
    } while (0)
#define WAIT_VM(N) asm volatile("s_waitcnt vmcnt(" #N ")" ::: "memory")

// ---------------------------------------------------------------------------
// fp32 -> bf16 cast (4 elems/thread)
// ---------------------------------------------------------------------------
__global__ void cast_bf16_kernel(const float* __restrict__ in, __hip_bfloat16* __restrict__ out) {
    int i = (blockIdx.x * blockDim.x + threadIdx.x) * 4;
    float4 v = *(const float4*)(in + i);
    out[i + 0] = __float2bfloat16(v.x);
    out[i + 1] = __float2bfloat16(v.y);
    out[i + 2] = __float2bfloat16(v.z);
    out[i + 3] = __float2bfloat16(v.w);
}

// ---------------------------------------------------------------------------
// W[K][N] fp32 -> Wt[N][K] bf16 (32x32 LDS tile transpose)
// ---------------------------------------------------------------------------
__global__ void transpose_cast_kernel(const float* __restrict__ w, __hip_bfloat16* __restrict__ wt,
                                      int K, int N) {
    __shared__ float tile[32][33];
    int n0 = blockIdx.x * 32, k0 = blockIdx.y * 32;
    int tx = threadIdx.x;  // 0..31
    int ty = threadIdx.y;  // 0..7
#pragma unroll
    for (int r = 0; r < 4; r++) {
        int k = k0 + ty + r * 8;
        tile[ty + r * 8][tx] = w[(size_t)k * N + n0 + tx];
    }
    __syncthreads();
#pragma unroll
    for (int r = 0; r < 4; r++) {
        int n = n0 + ty + r * 8;
        wt[(size_t)n * K + k0 + tx] = __float2bfloat16(tile[tx][ty + r * 8]);
    }
}

// ===========================================================================
// BK=64 XOR-swizzled GEMM core, 128x128 tile (known-good ~687 TF).
// ===========================================================================
template <typename EPILOGUE>
__device__ __forceinline__ void gemm128_bk64(
    const __hip_bfloat16* __restrict__ A, const __hip_bfloat16* __restrict__ Bt,
    int m0, int n0, int K, __hip_bfloat16* As, __hip_bfloat16* Bs, EPILOGUE epi) {
    int tid = threadIdx.x;
    int wave = tid >> 6, lane = tid & 63;
    int l15 = lane & 15, quad = lane >> 4;

    int lr = lane >> 3;                    // 0..7 row within 8-row group
    int c8 = (lane & 7) ^ lr;              // global chunk index for this lane
    const __hip_bfloat16* aG = A + (size_t)(m0 + wave * 8 + lr) * K + c8 * 8;
    const __hip_bfloat16* bG = Bt + (size_t)(n0 + wave * 8 + lr) * K + c8 * 8;
    __hip_bfloat16* aL = As + wave * 512;  // (wave*8 rows)*64
    __hip_bfloat16* bL = Bs + wave * 512;

    int wm = wave & 1, wn = wave >> 1;
    int e3 = l15 & 7;
    int s0 = (quad ^ e3) * 8;              // kh=0 slot offset (elements)
    int s1 = ((4 + quad) ^ e3) * 8;        // kh=1
    const __hip_bfloat16* afr = As + (wm * 64 + l15) * 64;
    const __hip_bfloat16* bfr = Bs + (wn * 64 + l15) * 64;

    f32x4 acc[4][4];
#pragma unroll
    for (int mi = 0; mi < 4; mi++)
#pragma unroll
        for (int ni = 0; ni < 4; ni++) acc[mi][ni] = (f32x4){0.f, 0.f, 0.f, 0.f};

    for (int k0 = 0; k0 < K; k0 += 64) {
#pragma unroll
        for (int i = 0; i < 4; i++) {
            gld_lds16(aG + k0 + (size_t)(i * 32) * K, aL + i * 2048);
            gld_lds16(bG + k0 + (size_t)(i * 32) * K, bL + i * 2048);
        }
        __syncthreads();
        bf16x8 a0[4], b0[4], a1[4], b1[4];
#pragma unroll
        for (int mi = 0; mi < 4; mi++) {
            a0[mi] = *(const bf16x8*)(afr + mi * 1024 + s0);
            a1[mi] = *(const bf16x8*)(afr + mi * 1024 + s1);
        }
#pragma unroll
        for (int ni = 0; ni < 4; ni++) {
            b0[ni] = *(const bf16x8*)(bfr + ni * 1024 + s0);
            b1[ni] = *(const bf16x8*)(bfr + ni * 1024 + s1);
        }
#pragma unroll
        for (int mi = 0; mi < 4; mi++)
#pragma unroll
            for (int ni = 0; ni < 4; ni++) {
                acc[mi][ni] = MFMA16(a0[mi], b0[ni], acc[mi][ni]);
                acc[mi][ni] = MFMA16(a1[mi], b1[ni], acc[mi][ni]);
            }
        __syncthreads();
    }
    epi(acc, wm, wn, l15, quad);
}

// ---------------------------------------------------------------------------
// Tiled QKV GEMM with FUSED RoPE epilogue.
// M=4096 (b*2048+s), N=6144 (Q|K|V), K=4096.
// Tiles are head-aligned (128 wide): Q tiles n0<4096, K tiles 4096..5119,
// V tiles >=5120. For Q/K tiles the epilogue exchanges the (d, d+64) rope
// partner through the (now dead) 32KB GEMM LDS and writes rope'd bf16.
// Math path identical to the old separate rope kernel: bf16-round ->
// fp32 rope (exp2f/__sincosf) -> bf16 store.
// V written tile-transposed: Vtt[b][kh][s>>6][d][s&63].
// ---------------------------------------------------------------------------
__global__ __launch_bounds__(256) void gemm_qkv_kernel(
    const __hip_bfloat16* __restrict__ Xb,
    const __hip_bfloat16* __restrict__ Wt,   // [6144][4096]
    const int* __restrict__ pos,
    __hip_bfloat16* __restrict__ Qraw,
    __hip_bfloat16* __restrict__ Kraw,
    __hip_bfloat16* __restrict__ Vtt) {
    __shared__ __hip_bfloat16 smem[128 * 128];   // As | Bs, reused as 128x128 exchange
    __hip_bfloat16* As = smem;
    __hip_bfloat16* Bs = smem + 128 * 64;
    int m0 = blockIdx.y * 128, n0 = blockIdx.x * 128;
    gemm128_bk64(Xb, Wt, m0, n0, 4096, As, Bs,
        [&](f32x4 (&acc)[4][4], int wm, int wn, int l15, int quad) {
            int bb = m0 >> 11;             // batch (tile never crosses the 2048 boundary)
            if (n0 >= 5120) {
                // ---- V tile: unchanged transposed write
#pragma unroll
                for (int mi = 0; mi < 4; mi++) {
#pragma unroll
                    for (int ni = 0; ni < 4; ni++) {
                        int n2 = n0 - 5120 + wn * 64 + ni * 16 + l15;
                        int hh = n2 >> 7, d = n2 & 127;
#pragma unroll
                        for (int r = 0; r < 4; r++) {
                            int m = m0 + wm * 64 + mi * 16 + quad * 4 + r;
                            int s = m & 2047;
                            __hip_bfloat16 hv = __float2bfloat16(acc[mi][ni][r]);
                            Vtt[((((size_t)(bb * 8 + hh)) * 32 + (s >> 6)) * 128 + d) * 64 + (s & 63)] = hv;
                        }
                    }
                }
            } else {
                // ---- Q or K tile: rope-fused epilogue
                // pass 1: store bf16-rounded acc into the exchange buffer.
                // layout: ex[mloc][ (chunk ^ (mloc&7))*8 + e ], chunk = nloc>>3, e = nloc&7
                // (8-elem XOR swizzle: stores 2-way/free, partner reads ~2-way/free)
#pragma unroll
                for (int mi = 0; mi < 4; mi++)
#pragma unroll
                    for (int ni = 0; ni < 4; ni++) {
                        int nloc = wn * 64 + ni * 16 + l15;
#pragma unroll
                        for (int r = 0; r < 4; r++) {
                            int mloc = wm * 64 + mi * 16 + quad * 4 + r;
                            int ch = (nloc >> 3) ^ (mloc & 7);
                            smem[mloc * 128 + ch * 8 + (nloc & 7)] = __float2bfloat16(acc[mi][ni][r]);
                        }
                    }
                __syncthreads();

                bool isQ = (n0 < 4096);
                size_t headbase = isQ
                    ? (size_t)(bb * 32 + (n0 >> 7)) * 2048
                    : (size_t)(bb * 8 + ((n0 - 4096) >> 7)) * 2048;
                __hip_bfloat16* dst = isQ ? Qraw : Kraw;

                float inv4[4];
#pragma unroll
                for (int ni = 0; ni < 4; ni++)
                    inv4[ni] = exp2f(-(float)(ni * 16 + l15) * 0.31143075889f);  // THETA^(-d0/64)

#pragma unroll
                for (int mi = 0; mi < 4; mi++) {
#pragma unroll
                    for (int r = 0; r < 4; r++) {
                        int mloc = wm * 64 + mi * 16 + quad * 4 + r;
                        int s = (m0 & 2047) + mloc;
                        float p = (float)pos[bb * 2048 + s];
                        __hip_bfloat16* drow = dst + (headbase + s) * 128;
#pragma unroll
                        for (int ni = 0; ni < 4; ni++) {
                            int nloc = wn * 64 + ni * 16 + l15;
                            int ploc = nloc ^ 64;
                            int pch = (ploc >> 3) ^ (mloc & 7);
                            float partner = __bfloat162float(smem[mloc * 128 + pch * 8 + (ploc & 7)]);
                            float own = __bfloat162float(__float2bfloat16(acc[mi][ni][r]));
                            float ang = p * inv4[ni];
                            float sn, cs;
                            __sincosf(ang, &sn, &cs);
                            float val = (nloc < 64) ? (own * cs - partner * sn)
                                                    : (own * cs + partner * sn);
                            drow[nloc] = __float2bfloat16(val);
                        }
                    }
                }
            }
        });
}

// ===========================================================================
// 256x256 8-phase core — gemm_out only (16x16=256-block grid, 1 block/CU,
// measured ≈ 128² core; kept for its perfectly quantized grid).
// ===========================================================================
constexpr int TILE = 256 * 64;  // elems per operand per buffer

template <typename EPILOGUE>
__device__ __forceinline__ void gemm256_8phase(
    const __hip_bfloat16* __restrict__ A, const __hip_bfloat16* __restrict__ Bt,
    int m0, int n0, int K, __hip_bfloat16* As, __hip_bfloat16* Bs, EPILOGUE epi) {
    int tid = threadIdx.x;
    int wave = tid >> 6, lane = tid & 63;
    int l15 = lane & 15, quad = lane >> 4;
    int wr = wave >> 2, wc = wave & 3;

    int lr = lane >> 3;
    int c8 = (lane & 7) ^ lr;
    const __hip_bfloat16* aG = A + (size_t)(m0 + wave * 8 + lr) * K + c8 * 8;
    const __hip_bfloat16* bG = Bt + (size_t)(n0 + wave * 8 + lr) * K + c8 * 8;
    int stRow = wave * 8;

    int e3 = l15 & 7;
    int s0 = (quad ^ e3) * 8;
    int s1 = ((4 + quad) ^ e3) * 8;

    f32x4 acc[8][4];
#pragma unroll
    for (int mi = 0; mi < 8; mi++)
#pragma unroll
        for (int ni = 0; ni < 4; ni++) acc[mi][ni] = (f32x4){0.f, 0.f, 0.f, 0.f};

    const int NT = K >> 6;

    auto stA = [&](int buf, int kt, int i) {
        gld_lds16(aG + (size_t)kt * 64 + (size_t)(i * 64) * K,
                  As + buf * TILE + (stRow + i * 64) * 64);
    };
    auto stB = [&](int buf, int kt, int i) {
        gld_lds16(bG + (size_t)kt * 64 + (size_t)(i * 64) * K,
                  Bs + buf * TILE + (stRow + i * 64) * 64);
    };

#pragma unroll
    for (int i = 0; i < 4; i++) stA(0, 0, i);
#pragma unroll
    for (int i = 0; i < 4; i++) stB(0, 0, i);
    {
        int k1 = (1 < NT) ? 1 : 0;
#pragma unroll
        for (int i = 0; i < 4; i++) stA(1, k1, i);
    }
    WAIT_VM(4);
    RAW_BARRIER();

    int cur = 0;
    for (int t = 0; t < NT; ++t) {
        int ktB = (t + 1 < NT) ? t + 1 : NT - 1;
        int ktA = (t + 2 < NT) ? t + 2 : NT - 1;
        const __hip_bfloat16* af = As + cur * TILE + (wr * 128 + l15) * 64;
        const __hip_bfloat16* bf = Bs + cur * TILE + (wc * 64 + l15) * 64;
        bf16x8 a0[4][2], a1[4][2], b0[2][2], b1[2][2];

        // ---- phase 1: Q(0,0)
#pragma unroll
        for (int mi = 0; mi < 4; mi++) {
            a0[mi][0] = *(const bf16x8*)(af + mi * 1024 + s0);
            a0[mi][1] = *(const bf16x8*)(af + mi * 1024 + s1);
        }
#pragma unroll
        for (int ni = 0; ni < 2; ni++) {
            b0[ni][0] = *(const bf16x8*)(bf + ni * 1024 + s0);
            b0[ni][1] = *(const bf16x8*)(bf + ni * 1024 + s1);
        }
        stB(cur ^ 1, ktB, 0);
        stB(cur ^ 1, ktB, 1);
        RAW_BARRIER();
        WAIT_LGKM0();
        __builtin_amdgcn_s_setprio(1);
#pragma unroll
        for (int mi = 0; mi < 4; mi++)
#pragma unroll
            for (int ni = 0; ni < 2; ni++) {
                acc[mi][ni] = MFMA16(a0[mi][0], b0[ni][0], acc[mi][ni]);
                acc[mi][ni] = MFMA16(a0[mi][1], b0[ni][1], acc[mi][ni]);
            }
        __builtin_amdgcn_s_setprio(0);
        RAW_BARRIER();

        // ---- phase 2: Q(1,0)
#pragma unroll
        for (int mi = 0; mi < 4; mi++) {
            a1[mi][0] = *(const bf16x8*)(af + (mi + 4) * 1024 + s0);
            a1[mi][1] = *(const bf16x8*)(af + (mi + 4) * 1024 + s1);
        }
        stB(cur ^ 1, ktB, 2);
        stB(cur ^ 1, ktB, 3);
        RAW_BARRIER();
        WAIT_LGKM0();
        __builtin_amdgcn_s_setprio(1);
#pragma unroll
        for (int mi = 0; mi < 4; mi++)
#pragma unroll
            for (int ni = 0; ni < 2; ni++) {
                acc[mi + 4][ni] = MFMA16(a1[mi][0], b0[ni][0], acc[mi + 4][ni]);
                acc[mi + 4][ni] = MFMA16(a1[mi][1], b0[ni][1], acc[mi + 4][ni]);
            }
        __builtin_amdgcn_s_setprio(0);
        RAW_BARRIER();

        // ---- phase 3: Q(0,1)
#pragma unroll
        for (int ni = 0; ni < 2; ni++) {
            b1[ni][0] = *(const bf16x8*)(bf + (ni + 2) * 1024 + s0);
            b1[ni][1] = *(const bf16x8*)(bf + (ni + 2) * 1024 + s1);
        }
        stA(cur, ktA, 0);
        stA(cur, ktA, 1);
        RAW_BARRIER();
        WAIT_LGKM0();
        __builtin_amdgcn_s_setprio(1);
#pragma unroll
        for (int mi = 0; mi < 4; mi++)
#pragma unroll
            for (int ni = 0; ni < 2; ni++) {
                acc[mi][ni + 2] = MFMA16(a0[mi][0], b1[ni][0], acc[mi][ni + 2]);
                acc[mi][ni + 2] = MFMA16(a0[mi][1], b1[ni][1], acc[mi][ni + 2]);
            }
        __builtin_amdgcn_s_setprio(0);
        RAW_BARRIER();

        // ---- phase 4: Q(1,1) + counted vmcnt
        stA(cur, ktA, 2);
        stA(cur, ktA, 3);
        RAW_BARRIER();
        __builtin_amdgcn_s_setprio(1);
#pragma unroll
        for (int mi = 0; mi < 4; mi++)
#pragma unroll
            for (int ni = 0; ni < 2; ni++) {
                acc[mi + 4][ni + 2] = MFMA16(a1[mi][0], b1[ni][0], acc[mi + 4][ni + 2]);
                acc[mi + 4][ni + 2] = MFMA16(a1[mi][1], b1[ni][1], acc[mi + 4][ni + 2]);
            }
        __builtin_amdgcn_s_setprio(0);
        WAIT_VM(4);
        RAW_BARRIER();
        cur ^= 1;
    }
    WAIT_VM(0);
    epi(acc, wr, wc, l15, quad);
}

// ---------------------------------------------------------------------------
// Tiled output GEMM: out[m][n] = AO[m][:] . Wot[n][:], fp32 out. M=N=K=4096.
// ---------------------------------------------------------------------------
__global__ __launch_bounds__(512, 2) void gemm_out_kernel(
    const __hip_bfloat16* __restrict__ A, const __hip_bfloat16* __restrict__ Bt,
    float* __restrict__ C) {
    __shared__ __hip_bfloat16 As[2 * TILE];
    __shared__ __hip_bfloat16 Bs[2 * TILE];
    int m0 = blockIdx.y * 256, n0 = blockIdx.x * 256;
    gemm256_8phase(A, Bt, m0, n0, 4096, As, Bs,
        [&](f32x4 (&acc)[8][4], int wr, int wc, int l15, int quad) {
            const int N = 4096;
#pragma unroll
            for (int mi = 0; mi < 8; mi++) {
#pragma unroll
                for (int ni = 0; ni < 4; ni++) {
                    int n = n0 + wc * 64 + ni * 16 + l15;
#pragma unroll
                    for (int r = 0; r < 4; r++) {
                        int m = m0 + wr * 128 + mi * 16 + quad * 4 + r;
                        C[(size_t)m * N + n] = acc[mi][ni][r];
                    }
                }
            }
        });
}

// ---------------------------------------------------------------------------
// Flash attention v6 = v4 (proven single-buffer structure) with:
//  - Pl re-packed to stride 64 with 8-elem XOR chunk swizzle (write at
//    chunk^(q&7), read at chunk^(l15&7): both sides ~2-way = free) ->
//    LDS exactly 40KB -> 4 blocks/CU (was 41.2KB -> 3 blocks/CU).
//  - __launch_bounds__(256,4) to cap VGPR at 128 for the 4-block residency.
//  - T5 setprio around QK and PV MFMA clusters (attn-positive, m191).
// ---------------------------------------------------------------------------
__global__ __launch_bounds__(256, 4) void attn_kernel(
    const __hip_bfloat16* __restrict__ Qb, const __hip_bfloat16* __restrict__ Kb,
    const __hip_bfloat16* __restrict__ Vtt, __hip_bfloat16* __restrict__ AO) {
    const int S = 2048, D = 128;
    __shared__ __hip_bfloat16 Ks[64 * 128];
    __shared__ __hip_bfloat16 Vs[128 * 64];
    __shared__ __hip_bfloat16 Pl[4][16][64];

    int tid = threadIdx.x;
    int wave = tid >> 6, lane = tid & 63;
    int l15 = lane & 15, quad = lane >> 4;
    int base = blockIdx.x * 64;
    int i0 = base + wave * 16;
    int h = blockIdx.y, b = blockIdx.z;
    int kh = h >> 2;
    const __hip_bfloat16* Qh = Qb + (size_t)(b * 32 + h) * S * D;
    const __hip_bfloat16* Kh = Kb + (size_t)(b * 8 + kh) * S * D;
    const __hip_bfloat16* Vh = Vtt + (size_t)(b * 8 + kh) * S * D;

    bf16x8 qf[4];
    {
        const __hip_bfloat16* qrow = Qh + (size_t)(i0 + l15) * D + quad * 8;
#pragma unroll
        for (int kk = 0; kk < 4; kk++) qf[kk] = *(const bf16x8*)(qrow + kk * 32);
    }
    f32x4 o[8];
#pragma unroll
    for (int f = 0; f < 8; f++) o[f] = (f32x4){0.f, 0.f, 0.f, 0.f};
    float lrow[4] = {0.f, 0.f, 0.f, 0.f};

    int kst = (base > 1023) ? ((base - 1023) & ~63) : 0;
    const float c2 = 0.12751878882f;  // (1/sqrt(128)) * log2(e)
    int e3 = l15 & 7;

    for (int key0 = kst; key0 <= base; key0 += 64) {
#pragma unroll
        for (int i = 0; i < 4; i++) {
            int rb = wave * 16 + i * 4;
            int row = rb + (lane >> 4);
            int c = (lane & 15) ^ (row & 7);
            gld_lds16(Kh + (size_t)(key0 + row) * 128 + c * 8, Ks + rb * 128);
        }
        const __hip_bfloat16* Vtile = Vh + (size_t)(key0 >> 6) * (128 * 64);
#pragma unroll
        for (int i = 0; i < 4; i++) {
            int db = wave * 32 + i * 8;
            int row = db + (lane >> 3);
            int c = (lane & 7) ^ (row & 7);
            gld_lds16(Vtile + (size_t)row * 64 + c * 8, Vs + db * 64);
        }
        __syncthreads();

        bool alive = (key0 <= i0 + 15) && (key0 + 63 >= i0 - 1023);
        if (alive) {
            f32x4 sc[4];
            __builtin_amdgcn_s_setprio(1);
#pragma unroll
            for (int kb = 0; kb < 4; kb++) {
                sc[kb] = (f32x4){0.f, 0.f, 0.f, 0.f};
                const __hip_bfloat16* krow = Ks + (kb * 16 + l15) * 128;
#pragma unroll
                for (int kk = 0; kk < 4; kk++) {
                    int slot = ((kk << 2) | quad) ^ e3;
                    bf16x8 kf = *(const bf16x8*)(krow + slot * 8);
                    sc[kb] = MFMA16(qf[kk], kf, sc[kb]);
                }
            }
            __builtin_amdgcn_s_setprio(0);
            bool interior = (key0 + 63 <= i0) && (key0 >= i0 - 1008);
            if (interior) {
#pragma unroll
                for (int kb = 0; kb < 4; kb++)
#pragma unroll
                    for (int r = 0; r < 4; r++) {
                        float p = __builtin_amdgcn_exp2f(sc[kb][r] * c2);
                        lrow[r] += p;
                        int q = quad * 4 + r;
                        Pl[wave][q][((kb * 2 + (l15 >> 3)) ^ (q & 7)) * 8 + (l15 & 7)] = __float2bfloat16(p);
                    }
            } else {
#pragma unroll
                for (int kb = 0; kb < 4; kb++)
#pragma unroll
                    for (int r = 0; r < 4; r++) {
                        int i = i0 + quad * 4 + r;
                        int j = key0 + kb * 16 + l15;
                        float v = (j <= i && i - j < 1024) ? sc[kb][r] * c2 : -1e30f;
                        float p = __builtin_amdgcn_exp2f(v);
                        lrow[r] += p;
                        int q = quad * 4 + r;
                        Pl[wave][q][((kb * 2 + (l15 >> 3)) ^ (q & 7)) * 8 + (l15 & 7)] = __float2bfloat16(p);
                    }
            }
            // read back: row l15, k-chunk quad (pf0) / 4+quad (pf1), XOR row&7
            bf16x8 pf0 = *(const bf16x8*)(&Pl[wave][l15][(quad ^ (l15 & 7)) * 8]);
            bf16x8 pf1 = *(const bf16x8*)(&Pl[wave][l15][((4 + quad) ^ (l15 & 7)) * 8]);
            int s0 = quad ^ e3, s1 = (4 + quad) ^ e3;
            __builtin_amdgcn_s_setprio(1);
#pragma unroll
            for (int f = 0; f < 8; f++) {
                const __hip_bfloat16* vrow = Vs + (f * 16 + l15) * 64;
                bf16x8 v0 = *(const bf16x8*)(vrow + s0 * 8);
                bf16x8 v1 = *(const bf16x8*)(vrow + s1 * 8);
                o[f] = MFMA16(pf0, v0, o[f]);
                o[f] = MFMA16(pf1, v1, o[f]);
            }
            __builtin_amdgcn_s_setprio(0);
        }
        __syncthreads();
    }

#pragma unroll
    for (int r = 0; r < 4; r++) {
#pragma unroll
        for (int msk = 1; msk < 16; msk <<= 1) lrow[r] += __shfl_xor(lrow[r], msk, 64);
    }
#pragma unroll
    for (int r = 0; r < 4; r++) {
        int srow = i0 + quad * 4 + r;
        float invl = 1.f / lrow[r];
        __hip_bfloat16* orow = AO + ((size_t)(b * 2048 + srow) * 4096) + h * 128;
#pragma unroll
        for (int f = 0; f < 8; f++) orow[f * 16 + l15] = __float2bfloat16(o[f][r] * invl);
    }
}

// ---------------------------------------------------------------------------
extern "C" void kernel_launch(void* const* d_in, const int* in_sizes, int n_in,
                              void* d_out, int out_size, void* d_ws, size_t ws_size,
                              hipStream_t stream) {
    (void)in_sizes; (void)n_in; (void)out_size;
    const float* hidden = (const float*)d_in[0];
    const int* pos = (const int*)d_in[1];
    const float* wq = (const float*)d_in[2];
    const float* wk = (const float*)d_in[3];
    const float* wv = (const float*)d_in[4];
    const float* wo = (const float*)d_in[5];
    float* out = (float*)d_out;

    const int M = 4096;  // B*S
    char* ws = (char*)d_ws;
    size_t off = 0;
    auto alloc = [&](size_t bytes) { char* p = ws + off; off += bytes; return p; };
    __hip_bfloat16* Xb    = (__hip_bfloat16*)alloc((size_t)M * 4096 * 2);
    __hip_bfloat16* Wqkvt = (__hip_bfloat16*)alloc((size_t)6144 * 4096 * 2);
    __hip_bfloat16* Wot   = (__hip_bfloat16*)alloc((size_t)4096 * 4096 * 2);
    __hip_bfloat16* Qb    = (__hip_bfloat16*)alloc((size_t)M * 4096 * 2);
    __hip_bfloat16* Kb    = (__hip_bfloat16*)alloc((size_t)M * 1024 * 2);
    __hip_bfloat16* Vtt   = (__hip_bfloat16*)alloc((size_t)M * 1024 * 2);
    __hip_bfloat16* AO    = (__hip_bfloat16*)alloc((size_t)M * 4096 * 2);
    if (off > ws_size) return;

    cast_bf16_kernel<<<(M * 4096) / 1024, 256, 0, stream>>>(hidden, Xb);
    dim3 tb(32, 8);
    transpose_cast_kernel<<<dim3(128, 128), tb, 0, stream>>>(wq, Wqkvt, 4096, 4096);
    transpose_cast_kernel<<<dim3(32, 128),  tb, 0, stream>>>(wk, Wqkvt + (size_t)4096 * 4096, 4096, 1024);
    transpose_cast_kernel<<<dim3(32, 128),  tb, 0, stream>>>(wv, Wqkvt + (size_t)5120 * 4096, 4096, 1024);
    transpose_cast_kernel<<<dim3(128, 128), tb, 0, stream>>>(wo, Wot, 4096, 4096);

    // RoPE is fused into the qkv epilogue — no separate rope launches.
    gemm_qkv_kernel<<<dim3(48, 32), 256, 0, stream>>>(Xb, Wqkvt, pos, Qb, Kb, Vtt);

    attn_kernel<<<dim3(32, 32, 2), 256, 0, stream>>>(Qb, Kb, Vtt, AO);

    gemm_out_kernel<<<dim3(16, 16), 512, 0, stream>>>(AO, Wot, out);
}

// Round 6
// 772.011 us; speedup vs baseline: 1.2804x; 1.2804x over previous
//
#include <hip/hip_runtime.h>
#include <hip/hip_bf16.h>
#include <math.h>

typedef __attribute__((ext_vector_type(8))) __bf16 bf16x8;
typedef __attribute__((ext_vector_type(4))) float f32x4;

#define MFMA16(a, b, c) __builtin_amdgcn_mfma_f32_16x16x32_bf16((a), (b), (c), 0, 0, 0)

__device__ inline void gld_lds16(const __hip_bfloat16* g, __hip_bfloat16* l) {
    __builtin_amdgcn_global_load_lds(
        (const __attribute__((address_space(1))) void*)g,
        (__attribute__((address_space(3))) void*)l, 16, 0, 0);
}

#define RAW_BARRIER() __builtin_amdgcn_s_barrier()
#define WAIT_LGKM0()                                          \
    do {                                                      \
        asm volatile("s_waitcnt lgkmcnt(0)" ::: "memory");    \
        __builtin_amdgcn_sched_barrier(0);                    \
    } while (0)
#define WAIT_VM(N) asm volatile("s_waitcnt vmcnt(" #N ")" ::: "memory")

// ---------------------------------------------------------------------------
// fp32 -> bf16 cast (4 elems/thread)
// ---------------------------------------------------------------------------
__global__ void cast_bf16_kernel(const float* __restrict__ in, __hip_bfloat16* __restrict__ out) {
    int i = (blockIdx.x * blockDim.x + threadIdx.x) * 4;
    float4 v = *(const float4*)(in + i);
    out[i + 0] = __float2bfloat16(v.x);
    out[i + 1] = __float2bfloat16(v.y);
    out[i + 2] = __float2bfloat16(v.z);
    out[i + 3] = __float2bfloat16(v.w);
}

// ---------------------------------------------------------------------------
// W[K][N] fp32 -> Wt[N][K] bf16 (32x32 LDS tile transpose)
// ---------------------------------------------------------------------------
__global__ void transpose_cast_kernel(const float* __restrict__ w, __hip_bfloat16* __restrict__ wt,
                                      int K, int N) {
    __shared__ float tile[32][33];
    int n0 = blockIdx.x * 32, k0 = blockIdx.y * 32;
    int tx = threadIdx.x;  // 0..31
    int ty = threadIdx.y;  // 0..7
#pragma unroll
    for (int r = 0; r < 4; r++) {
        int k = k0 + ty + r * 8;
        tile[ty + r * 8][tx] = w[(size_t)k * N + n0 + tx];
    }
    __syncthreads();
#pragma unroll
    for (int r = 0; r < 4; r++) {
        int n = n0 + ty + r * 8;
        wt[(size_t)n * K + k0 + tx] = __float2bfloat16(tile[tx][ty + r * 8]);
    }
}

// ===========================================================================
// BK=64 XOR-swizzled GEMM core, 128x128 tile (known-good, 302 µs for qkv).
// ===========================================================================
template <typename EPILOGUE>
__device__ __forceinline__ void gemm128_bk64(
    const __hip_bfloat16* __restrict__ A, const __hip_bfloat16* __restrict__ Bt,
    int m0, int n0, int K, __hip_bfloat16* As, __hip_bfloat16* Bs, EPILOGUE epi) {
    int tid = threadIdx.x;
    int wave = tid >> 6, lane = tid & 63;
    int l15 = lane & 15, quad = lane >> 4;

    int lr = lane >> 3;                    // 0..7 row within 8-row group
    int c8 = (lane & 7) ^ lr;              // global chunk index for this lane
    const __hip_bfloat16* aG = A + (size_t)(m0 + wave * 8 + lr) * K + c8 * 8;
    const __hip_bfloat16* bG = Bt + (size_t)(n0 + wave * 8 + lr) * K + c8 * 8;
    __hip_bfloat16* aL = As + wave * 512;  // (wave*8 rows)*64
    __hip_bfloat16* bL = Bs + wave * 512;

    int wm = wave & 1, wn = wave >> 1;
    int e3 = l15 & 7;
    int s0 = (quad ^ e3) * 8;              // kh=0 slot offset (elements)
    int s1 = ((4 + quad) ^ e3) * 8;        // kh=1
    const __hip_bfloat16* afr = As + (wm * 64 + l15) * 64;
    const __hip_bfloat16* bfr = Bs + (wn * 64 + l15) * 64;

    f32x4 acc[4][4];
#pragma unroll
    for (int mi = 0; mi < 4; mi++)
#pragma unroll
        for (int ni = 0; ni < 4; ni++) acc[mi][ni] = (f32x4){0.f, 0.f, 0.f, 0.f};

    for (int k0 = 0; k0 < K; k0 += 64) {
#pragma unroll
        for (int i = 0; i < 4; i++) {
            gld_lds16(aG + k0 + (size_t)(i * 32) * K, aL + i * 2048);
            gld_lds16(bG + k0 + (size_t)(i * 32) * K, bL + i * 2048);
        }
        __syncthreads();
        bf16x8 a0[4], b0[4], a1[4], b1[4];
#pragma unroll
        for (int mi = 0; mi < 4; mi++) {
            a0[mi] = *(const bf16x8*)(afr + mi * 1024 + s0);
            a1[mi] = *(const bf16x8*)(afr + mi * 1024 + s1);
        }
#pragma unroll
        for (int ni = 0; ni < 4; ni++) {
            b0[ni] = *(const bf16x8*)(bfr + ni * 1024 + s0);
            b1[ni] = *(const bf16x8*)(bfr + ni * 1024 + s1);
        }
#pragma unroll
        for (int mi = 0; mi < 4; mi++)
#pragma unroll
            for (int ni = 0; ni < 4; ni++) {
                acc[mi][ni] = MFMA16(a0[mi], b0[ni], acc[mi][ni]);
                acc[mi][ni] = MFMA16(a1[mi], b1[ni], acc[mi][ni]);
            }
        __syncthreads();
    }
    epi(acc, wm, wn, l15, quad);
}

// ---------------------------------------------------------------------------
// Tiled QKV GEMM (known-good, NO rope fusion): M=4096, N=6144, K=4096.
// V written tile-transposed: Vtt[b][kh][s>>6][d][s&63].
// ---------------------------------------------------------------------------
__global__ __launch_bounds__(256) void gemm_qkv_kernel(
    const __hip_bfloat16* __restrict__ Xb,
    const __hip_bfloat16* __restrict__ Wt,   // [6144][4096]
    __hip_bfloat16* __restrict__ Qraw,
    __hip_bfloat16* __restrict__ Kraw,
    __hip_bfloat16* __restrict__ Vtt) {
    __shared__ __hip_bfloat16 As[128 * 64];
    __shared__ __hip_bfloat16 Bs[128 * 64];
    int m0 = blockIdx.y * 128, n0 = blockIdx.x * 128;
    gemm128_bk64(Xb, Wt, m0, n0, 4096, As, Bs,
        [&](f32x4 (&acc)[4][4], int wm, int wn, int l15, int quad) {
#pragma unroll
            for (int mi = 0; mi < 4; mi++) {
#pragma unroll
                for (int ni = 0; ni < 4; ni++) {
                    int n = n0 + wn * 64 + ni * 16 + l15;
#pragma unroll
                    for (int r = 0; r < 4; r++) {
                        int m = m0 + wm * 64 + mi * 16 + quad * 4 + r;
                        int bb = m >> 11, s = m & 2047;
                        __hip_bfloat16 hv = __float2bfloat16(acc[mi][ni][r]);
                        if (n < 4096) {
                            int hh = n >> 7, d = n & 127;
                            Qraw[(((size_t)(bb * 32 + hh)) * 2048 + s) * 128 + d] = hv;
                        } else if (n < 5120) {
                            int n2 = n - 4096, hh = n2 >> 7, d = n2 & 127;
                            Kraw[(((size_t)(bb * 8 + hh)) * 2048 + s) * 128 + d] = hv;
                        } else {
                            int n2 = n - 5120, hh = n2 >> 7, d = n2 & 127;
                            Vtt[((((size_t)(bb * 8 + hh)) * 32 + (s >> 6)) * 128 + d) * 64 + (s & 63)] = hv;
                        }
                    }
                }
            }
        });
}

// ===========================================================================
// 256x256 8-phase core — gemm_out only (16x16=256-block grid, 1 block/CU).
// ===========================================================================
constexpr int TILE = 256 * 64;  // elems per operand per buffer

template <typename EPILOGUE>
__device__ __forceinline__ void gemm256_8phase(
    const __hip_bfloat16* __restrict__ A, const __hip_bfloat16* __restrict__ Bt,
    int m0, int n0, int K, __hip_bfloat16* As, __hip_bfloat16* Bs, EPILOGUE epi) {
    int tid = threadIdx.x;
    int wave = tid >> 6, lane = tid & 63;
    int l15 = lane & 15, quad = lane >> 4;
    int wr = wave >> 2, wc = wave & 3;

    int lr = lane >> 3;
    int c8 = (lane & 7) ^ lr;
    const __hip_bfloat16* aG = A + (size_t)(m0 + wave * 8 + lr) * K + c8 * 8;
    const __hip_bfloat16* bG = Bt + (size_t)(n0 + wave * 8 + lr) * K + c8 * 8;
    int stRow = wave * 8;

    int e3 = l15 & 7;
    int s0 = (quad ^ e3) * 8;
    int s1 = ((4 + quad) ^ e3) * 8;

    f32x4 acc[8][4];
#pragma unroll
    for (int mi = 0; mi < 8; mi++)
#pragma unroll
        for (int ni = 0; ni < 4; ni++) acc[mi][ni] = (f32x4){0.f, 0.f, 0.f, 0.f};

    const int NT = K >> 6;

    auto stA = [&](int buf, int kt, int i) {
        gld_lds16(aG + (size_t)kt * 64 + (size_t)(i * 64) * K,
                  As + buf * TILE + (stRow + i * 64) * 64);
    };
    auto stB = [&](int buf, int kt, int i) {
        gld_lds16(bG + (size_t)kt * 64 + (size_t)(i * 64) * K,
                  Bs + buf * TILE + (stRow + i * 64) * 64);
    };

#pragma unroll
    for (int i = 0; i < 4; i++) stA(0, 0, i);
#pragma unroll
    for (int i = 0; i < 4; i++) stB(0, 0, i);
    {
        int k1 = (1 < NT) ? 1 : 0;
#pragma unroll
        for (int i = 0; i < 4; i++) stA(1, k1, i);
    }
    WAIT_VM(4);
    RAW_BARRIER();

    int cur = 0;
    for (int t = 0; t < NT; ++t) {
        int ktB = (t + 1 < NT) ? t + 1 : NT - 1;
        int ktA = (t + 2 < NT) ? t + 2 : NT - 1;
        const __hip_bfloat16* af = As + cur * TILE + (wr * 128 + l15) * 64;
        const __hip_bfloat16* bf = Bs + cur * TILE + (wc * 64 + l15) * 64;
        bf16x8 a0[4][2], a1[4][2], b0[2][2], b1[2][2];

        // ---- phase 1: Q(0,0)
#pragma unroll
        for (int mi = 0; mi < 4; mi++) {
            a0[mi][0] = *(const bf16x8*)(af + mi * 1024 + s0);
            a0[mi][1] = *(const bf16x8*)(af + mi * 1024 + s1);
        }
#pragma unroll
        for (int ni = 0; ni < 2; ni++) {
            b0[ni][0] = *(const bf16x8*)(bf + ni * 1024 + s0);
            b0[ni][1] = *(const bf16x8*)(bf + ni * 1024 + s1);
        }
        stB(cur ^ 1, ktB, 0);
        stB(cur ^ 1, ktB, 1);
        RAW_BARRIER();
        WAIT_LGKM0();
        __builtin_amdgcn_s_setprio(1);
#pragma unroll
        for (int mi = 0; mi < 4; mi++)
#pragma unroll
            for (int ni = 0; ni < 2; ni++) {
                acc[mi][ni] = MFMA16(a0[mi][0], b0[ni][0], acc[mi][ni]);
                acc[mi][ni] = MFMA16(a0[mi][1], b0[ni][1], acc[mi][ni]);
            }
        __builtin_amdgcn_s_setprio(0);
        RAW_BARRIER();

        // ---- phase 2: Q(1,0)
#pragma unroll
        for (int mi = 0; mi < 4; mi++) {
            a1[mi][0] = *(const bf16x8*)(af + (mi + 4) * 1024 + s0);
            a1[mi][1] = *(const bf16x8*)(af + (mi + 4) * 1024 + s1);
        }
        stB(cur ^ 1, ktB, 2);
        stB(cur ^ 1, ktB, 3);
        RAW_BARRIER();
        WAIT_LGKM0();
        __builtin_amdgcn_s_setprio(1);
#pragma unroll
        for (int mi = 0; mi < 4; mi++)
#pragma unroll
            for (int ni = 0; ni < 2; ni++) {
                acc[mi + 4][ni] = MFMA16(a1[mi][0], b0[ni][0], acc[mi + 4][ni]);
                acc[mi + 4][ni] = MFMA16(a1[mi][1], b0[ni][1], acc[mi + 4][ni]);
            }
        __builtin_amdgcn_s_setprio(0);
        RAW_BARRIER();

        // ---- phase 3: Q(0,1)
#pragma unroll
        for (int ni = 0; ni < 2; ni++) {
            b1[ni][0] = *(const bf16x8*)(bf + (ni + 2) * 1024 + s0);
            b1[ni][1] = *(const bf16x8*)(bf + (ni + 2) * 1024 + s1);
        }
        stA(cur, ktA, 0);
        stA(cur, ktA, 1);
        RAW_BARRIER();
        WAIT_LGKM0();
        __builtin_amdgcn_s_setprio(1);
#pragma unroll
        for (int mi = 0; mi < 4; mi++)
#pragma unroll
            for (int ni = 0; ni < 2; ni++) {
                acc[mi][ni + 2] = MFMA16(a0[mi][0], b1[ni][0], acc[mi][ni + 2]);
                acc[mi][ni + 2] = MFMA16(a0[mi][1], b1[ni][1], acc[mi][ni + 2]);
            }
        __builtin_amdgcn_s_setprio(0);
        RAW_BARRIER();

        // ---- phase 4: Q(1,1) + counted vmcnt
        stA(cur, ktA, 2);
        stA(cur, ktA, 3);
        RAW_BARRIER();
        __builtin_amdgcn_s_setprio(1);
#pragma unroll
        for (int mi = 0; mi < 4; mi++)
#pragma unroll
            for (int ni = 0; ni < 2; ni++) {
                acc[mi + 4][ni + 2] = MFMA16(a1[mi][0], b1[ni][0], acc[mi + 4][ni + 2]);
                acc[mi + 4][ni + 2] = MFMA16(a1[mi][1], b1[ni][1], acc[mi + 4][ni + 2]);
            }
        __builtin_amdgcn_s_setprio(0);
        WAIT_VM(4);
        RAW_BARRIER();
        cur ^= 1;
    }
    WAIT_VM(0);
    epi(acc, wr, wc, l15, quad);
}

// ---------------------------------------------------------------------------
// Tiled output GEMM: out[m][n] = AO[m][:] . Wot[n][:], fp32 out. M=N=K=4096.
// ---------------------------------------------------------------------------
__global__ __launch_bounds__(512, 2) void gemm_out_kernel(
    const __hip_bfloat16* __restrict__ A, const __hip_bfloat16* __restrict__ Bt,
    float* __restrict__ C) {
    __shared__ __hip_bfloat16 As[2 * TILE];
    __shared__ __hip_bfloat16 Bs[2 * TILE];
    int m0 = blockIdx.y * 256, n0 = blockIdx.x * 256;
    gemm256_8phase(A, Bt, m0, n0, 4096, As, Bs,
        [&](f32x4 (&acc)[8][4], int wr, int wc, int l15, int quad) {
            const int N = 4096;
#pragma unroll
            for (int mi = 0; mi < 8; mi++) {
#pragma unroll
                for (int ni = 0; ni < 4; ni++) {
                    int n = n0 + wc * 64 + ni * 16 + l15;
#pragma unroll
                    for (int r = 0; r < 4; r++) {
                        int m = m0 + wr * 128 + mi * 16 + quad * 4 + r;
                        C[(size_t)m * N + n] = acc[mi][ni][r];
                    }
                }
            }
        });
}

// ---------------------------------------------------------------------------
// In-place RoPE on x[b][h][s][128] bf16 (separate kernel — fusion regressed).
// ---------------------------------------------------------------------------
__global__ void rope_kernel(__hip_bfloat16* __restrict__ x, const int* __restrict__ pos_ids,
                            int nheads) {
    int idx = blockIdx.x * blockDim.x + threadIdx.x;
    int d = idx & 63;
    int s = (idx >> 6) & 2047;
    int bh = idx >> 17;
    int b = bh / nheads;
    float p = (float)pos_ids[b * 2048 + s];
    float inv = exp2f(-(float)d * 0.31143075889f);  // THETA^(-d/64), log2(1e6)/64
    float ang = p * inv;
    float sn, cs;
    __sincosf(ang, &sn, &cs);
    size_t base = ((size_t)bh * 2048 + s) * 128;
    float x1 = __bfloat162float(x[base + d]);
    float x2 = __bfloat162float(x[base + d + 64]);
    x[base + d]      = __float2bfloat16(x1 * cs - x2 * sn);
    x[base + d + 64] = __float2bfloat16(x2 * cs + x1 * sn);
}

// ---------------------------------------------------------------------------
// Flash attention v7: 128 q-rows per block, 8 waves (16 rows each).
// Staging per tile (K 64x128, V 128x64) split across 8 waves -> K/V bytes
// staged per q-row HALVED vs v6, barriers per q-row halved. Wave-TLP/CU
// unchanged (2blk x 8w = 16w/CU, launch_bounds(512,4) caps VGPR at 128).
// LDS = 16+16+16 = 48 KB. Pl swizzle as v6.
// ---------------------------------------------------------------------------
__global__ __launch_bounds__(512, 4) void attn_kernel(
    const __hip_bfloat16* __restrict__ Qb, const __hip_bfloat16* __restrict__ Kb,
    const __hip_bfloat16* __restrict__ Vtt, __hip_bfloat16* __restrict__ AO) {
    const int S = 2048, D = 128;
    __shared__ __hip_bfloat16 Ks[64 * 128];
    __shared__ __hip_bfloat16 Vs[128 * 64];
    __shared__ __hip_bfloat16 Pl[8][16][64];

    int tid = threadIdx.x;
    int wave = tid >> 6, lane = tid & 63;
    int l15 = lane & 15, quad = lane >> 4;
    int base = blockIdx.x * 128;       // 128 q-rows per block
    int i0 = base + wave * 16;         // this wave's 16 q-rows
    int h = blockIdx.y, b = blockIdx.z;
    int kh = h >> 2;
    const __hip_bfloat16* Qh = Qb + (size_t)(b * 32 + h) * S * D;
    const __hip_bfloat16* Kh = Kb + (size_t)(b * 8 + kh) * S * D;
    const __hip_bfloat16* Vh = Vtt + (size_t)(b * 8 + kh) * S * D;

    bf16x8 qf[4];
    {
        const __hip_bfloat16* qrow = Qh + (size_t)(i0 + l15) * D + quad * 8;
#pragma unroll
        for (int kk = 0; kk < 4; kk++) qf[kk] = *(const bf16x8*)(qrow + kk * 32);
    }
    f32x4 o[8];
#pragma unroll
    for (int f = 0; f < 8; f++) o[f] = (f32x4){0.f, 0.f, 0.f, 0.f};
    float lrow[4] = {0.f, 0.f, 0.f, 0.f};

    // window for the whole block: rows [base, base+127]
    int kst = (base > 1023) ? ((base - 1023) & ~63) : 0;
    int kend = base + 64;  // last tile covers rows base+64 .. base+127
    const float c2 = 0.12751878882f;  // (1/sqrt(128)) * log2(e)
    int e3 = l15 & 7;

    for (int key0 = kst; key0 <= kend; key0 += 64) {
        // --- stage K: 8 waves x 2 inst x 4 rows = 64 rows
#pragma unroll
        for (int i = 0; i < 2; i++) {
            int rb = wave * 8 + i * 4;
            int row = rb + (lane >> 4);
            int c = (lane & 15) ^ (row & 7);
            gld_lds16(Kh + (size_t)(key0 + row) * 128 + c * 8, Ks + rb * 128);
        }
        // --- stage V (transposed tile): 8 waves x 2 inst x 8 rows = 128 rows
        const __hip_bfloat16* Vtile = Vh + (size_t)(key0 >> 6) * (128 * 64);
#pragma unroll
        for (int i = 0; i < 2; i++) {
            int db = wave * 16 + i * 8;
            int row = db + (lane >> 3);
            int c = (lane & 7) ^ (row & 7);
            gld_lds16(Vtile + (size_t)row * 64 + c * 8, Vs + db * 64);
        }
        __syncthreads();

        bool alive = (key0 <= i0 + 15) && (key0 + 63 >= i0 - 1023);
        if (alive) {
            f32x4 sc[4];
            __builtin_amdgcn_s_setprio(1);
#pragma unroll
            for (int kb = 0; kb < 4; kb++) {
                sc[kb] = (f32x4){0.f, 0.f, 0.f, 0.f};
                const __hip_bfloat16* krow = Ks + (kb * 16 + l15) * 128;
#pragma unroll
                for (int kk = 0; kk < 4; kk++) {
                    int slot = ((kk << 2) | quad) ^ e3;
                    bf16x8 kf = *(const bf16x8*)(krow + slot * 8);
                    sc[kb] = MFMA16(qf[kk], kf, sc[kb]);
                }
            }
            __builtin_amdgcn_s_setprio(0);
            bool interior = (key0 + 63 <= i0) && (key0 >= i0 - 1008);
            if (interior) {
#pragma unroll
                for (int kb = 0; kb < 4; kb++)
#pragma unroll
                    for (int r = 0; r < 4; r++) {
                        float p = __builtin_amdgcn_exp2f(sc[kb][r] * c2);
                        lrow[r] += p;
                        int q = quad * 4 + r;
                        Pl[wave][q][((kb * 2 + (l15 >> 3)) ^ (q & 7)) * 8 + (l15 & 7)] = __float2bfloat16(p);
                    }
            } else {
#pragma unroll
                for (int kb = 0; kb < 4; kb++)
#pragma unroll
                    for (int r = 0; r < 4; r++) {
                        int i = i0 + quad * 4 + r;
                        int j = key0 + kb * 16 + l15;
                        float v = (j <= i && i - j < 1024) ? sc[kb][r] * c2 : -1e30f;
                        float p = __builtin_amdgcn_exp2f(v);
                        lrow[r] += p;
                        int q = quad * 4 + r;
                        Pl[wave][q][((kb * 2 + (l15 >> 3)) ^ (q & 7)) * 8 + (l15 & 7)] = __float2bfloat16(p);
                    }
            }
            bf16x8 pf0 = *(const bf16x8*)(&Pl[wave][l15][(quad ^ (l15 & 7)) * 8]);
            bf16x8 pf1 = *(const bf16x8*)(&Pl[wave][l15][((4 + quad) ^ (l15 & 7)) * 8]);
            int s0 = quad ^ e3, s1 = (4 + quad) ^ e3;
            __builtin_amdgcn_s_setprio(1);
#pragma unroll
            for (int f = 0; f < 8; f++) {
                const __hip_bfloat16* vrow = Vs + (f * 16 + l15) * 64;
                bf16x8 v0 = *(const bf16x8*)(vrow + s0 * 8);
                bf16x8 v1 = *(const bf16x8*)(vrow + s1 * 8);
                o[f] = MFMA16(pf0, v0, o[f]);
                o[f] = MFMA16(pf1, v1, o[f]);
            }
            __builtin_amdgcn_s_setprio(0);
        }
        __syncthreads();
    }

#pragma unroll
    for (int r = 0; r < 4; r++) {
#pragma unroll
        for (int msk = 1; msk < 16; msk <<= 1) lrow[r] += __shfl_xor(lrow[r], msk, 64);
    }
#pragma unroll
    for (int r = 0; r < 4; r++) {
        int srow = i0 + quad * 4 + r;
        float invl = 1.f / lrow[r];
        __hip_bfloat16* orow = AO + ((size_t)(b * 2048 + srow) * 4096) + h * 128;
#pragma unroll
        for (int f = 0; f < 8; f++) orow[f * 16 + l15] = __float2bfloat16(o[f][r] * invl);
    }
}

// ---------------------------------------------------------------------------
extern "C" void kernel_launch(void* const* d_in, const int* in_sizes, int n_in,
                              void* d_out, int out_size, void* d_ws, size_t ws_size,
                              hipStream_t stream) {
    (void)in_sizes; (void)n_in; (void)out_size;
    const float* hidden = (const float*)d_in[0];
    const int* pos = (const int*)d_in[1];
    const float* wq = (const float*)d_in[2];
    const float* wk = (const float*)d_in[3];
    const float* wv = (const float*)d_in[4];
    const float* wo = (const float*)d_in[5];
    float* out = (float*)d_out;

    const int M = 4096;  // B*S
    char* ws = (char*)d_ws;
    size_t off = 0;
    auto alloc = [&](size_t bytes) { char* p = ws + off; off += bytes; return p; };
    __hip_bfloat16* Xb    = (__hip_bfloat16*)alloc((size_t)M * 4096 * 2);
    __hip_bfloat16* Wqkvt = (__hip_bfloat16*)alloc((size_t)6144 * 4096 * 2);
    __hip_bfloat16* Wot   = (__hip_bfloat16*)alloc((size_t)4096 * 4096 * 2);
    __hip_bfloat16* Qb    = (__hip_bfloat16*)alloc((size_t)M * 4096 * 2);
    __hip_bfloat16* Kb    = (__hip_bfloat16*)alloc((size_t)M * 1024 * 2);
    __hip_bfloat16* Vtt   = (__hip_bfloat16*)alloc((size_t)M * 1024 * 2);
    __hip_bfloat16* AO    = (__hip_bfloat16*)alloc((size_t)M * 4096 * 2);
    if (off > ws_size) return;

    cast_bf16_kernel<<<(M * 4096) / 1024, 256, 0, stream>>>(hidden, Xb);
    dim3 tb(32, 8);
    transpose_cast_kernel<<<dim3(128, 128), tb, 0, stream>>>(wq, Wqkvt, 4096, 4096);
    transpose_cast_kernel<<<dim3(32, 128),  tb, 0, stream>>>(wk, Wqkvt + (size_t)4096 * 4096, 4096, 1024);
    transpose_cast_kernel<<<dim3(32, 128),  tb, 0, stream>>>(wv, Wqkvt + (size_t)5120 * 4096, 4096, 1024);
    transpose_cast_kernel<<<dim3(128, 128), tb, 0, stream>>>(wo, Wot, 4096, 4096);

    gemm_qkv_kernel<<<dim3(48, 32), 256, 0, stream>>>(Xb, Wqkvt, Qb, Kb, Vtt);

    rope_kernel<<<(2 * 32 * 2048 * 64) / 256, 256, 0, stream>>>(Qb, pos, 32);
    rope_kernel<<<(2 * 8 * 2048 * 64) / 256, 256, 0, stream>>>(Kb, pos, 8);

    attn_kernel<<<dim3(16, 32, 2), 512, 0, stream>>>(Qb, Kb, Vtt, AO);

    gemm_out_kernel<<<dim3(16, 16), 512, 0, stream>>>(AO, Wot, out);
}